// Round 1
// baseline (154.660 us; speedup 1.0000x reference)
//
#include <hip/hip_runtime.h>

// StateSpaceDiffusionModel — MFMA formulation, round 3.
//
// Scalar collapse (HW-verified):
//   r_t = u_t + sum_{j=0}^{63} w_j r_{t-1-j},   y_t = sum_{j=0}^{63} g_j r_{t-j}
// NEW in this round: collapse the two serial triangular products per chunk.
// With S (lower-tri Toeplitz, s = IIR impulse resp.) and W (upper-tri Toeplitz):
//   old: E = u + W·p ; r = S·E        (2 LDS round-trips, 2 barriers / chunk)
//   new: r = A·p + S·u,  A = S·W      (1 LDS round-trip, 1 barrier / chunk)
// A is a dense per-head 64x64 computed ONCE in the prologue by MFMA (4-term
// hi/lo product -> ~2^-16 systematic error, negligible vs data-path error).
// u enters as a B-operand fragment loaded directly from global (hi/lo bf16).
// Main-loop barriers are raw s_barrier with lgkmcnt-only drain so the u
// prefetch and y stores stay in flight across barriers.
// Prologue is barrier-light: wave0 computes w,g by shuffle scans and s by a
// 63-step __shfl recurrence (no block barriers); 3 __syncthreads total.
//
// mfma_f32_16x16x32_bf16 layouts (m89/m120):
//   A[m][k]: m=lane&15, k=(lane>>4)*8+j (+32*tk)
//   B[k][n]: k=(lane>>4)*8+j (+32*tk), n=lane&15
//   C[m][n]: n=lane&15, m=(lane>>4)*4+reg

namespace {

constexpr int kH = 512;
constexpr int kL = 2048;
constexpr int kChunks = 32;
constexpr int kStride = 68;   // LDS row stride (floats): 68 = 4*17

typedef __attribute__((ext_vector_type(8))) short bf16x8;
typedef __attribute__((ext_vector_type(4))) float f32x4;

#define MFMA(A, B, C) __builtin_amdgcn_mfma_f32_16x16x32_bf16((A), (B), (C), 0, 0, 0)

__device__ inline unsigned int cvt_pk_bf16(float lo, float hi) {
  unsigned int r;
  asm("v_cvt_pk_bf16_f32 %0, %1, %2" : "=v"(r) : "v"(lo), "v"(hi));
  return r;
}

union B8U4 { bf16x8 v; unsigned int u[4]; };

// split 8 fp32 (two f32x4) into hi/lo bf16 fragments via packed RNE cvt
__device__ inline void cvt_split8(const f32x4 a, const f32x4 b, bf16x8& fh, bf16x8& fl) {
  B8U4 H, L;
  float x[8];
  #pragma unroll
  for (int j = 0; j < 4; ++j) { x[j] = a[j]; x[4 + j] = b[j]; }
  #pragma unroll
  for (int d = 0; d < 4; ++d) {
    const float x0 = x[2 * d], x1 = x[2 * d + 1];
    const unsigned int hp = cvt_pk_bf16(x0, x1);
    const float h0 = __uint_as_float(hp << 16);
    const float h1 = __uint_as_float(hp & 0xFFFF0000u);
    H.u[d] = hp;
    L.u[d] = cvt_pk_bf16(x0 - h0, x1 - h1);
  }
  fh = H.v; fl = L.v;
}

// Toeplitz A-operand fragment from a 128-tap array: value = tp[n0 - j]
__device__ inline void gen_frag(const float* tp, int n0, bf16x8& fh, bf16x8& fl) {
  float t[8];
  #pragma unroll
  for (int j = 0; j < 8; ++j) {
    const int n = n0 - j;
    t[j] = (n >= 0 && n < 127) ? tp[n] : 0.0f;
  }
  const f32x4 a = {t[0], t[1], t[2], t[3]};
  const f32x4 b = {t[4], t[5], t[6], t[7]};
  cvt_split8(a, b, fh, fl);
}

__global__ __launch_bounds__(256, 2)
void ssm_mfma_kernel(const float* __restrict__ u,
                     const float* __restrict__ kin,
                     float* __restrict__ y) {
  const int h    = blockIdx.x;
  const int tid  = threadIdx.x;
  const int wq   = tid >> 6;     // wave id = output row block
  const int lane = tid & 63;
  const int ln16 = lane & 15;    // batch col (B/C) / row m (A)
  const int quad = lane >> 4;

  __shared__ float sArr[64], gArr[64], wPad[128];
  __shared__ float taps[3][128];            // 0=S, 1=G2, 2=G1
  __shared__ float Abuf[64][kStride];       // A = S·W (dense, fp32)
  __shared__ float Rbuf[2][16][kStride];    // [buf][batch][time-in-chunk]

  // ---------------- prologue: wave 0 computes taps via shuffles ------------
  if (wq == 0) {
    const float kv = kin[h * 64 + lane];
    const float kc = fminf(fmaxf(kv, 0.0625f), 1.0f);
    float ks = kc;
    #pragma unroll
    for (int off = 32; off >= 1; off >>= 1) ks += __shfl_xor(ks, off);
    const float kn = kc / ks;
    const float cc = 1.0f / (1.0f + kn);
    // exclusive prefix product of cc across lanes
    float pp = cc;
    #pragma unroll
    for (int off = 1; off < 64; off <<= 1) {
      const float t = __shfl_up(pp, off);
      if (lane >= off) pp *= t;
    }
    float Pe = __shfl_up(pp, 1);
    if (lane == 0) Pe = 1.0f;
    const float w = (lane < 63) ? (kn * cc * Pe) : Pe;
    const float g = kv * Pe;
    // impulse response s_0..s_63: serial shuffle recurrence (wave-local)
    float s = (lane == 0) ? 1.0f : 0.0f;
    for (int rr = 0; rr < 63; ++rr) {
      const float sv = __shfl(s, rr);
      const float cf = __shfl(w, lane - 1 - rr);
      if (lane > rr) s = fmaf(cf, sv, s);
    }
    sArr[lane] = s;
    gArr[lane] = g;
    wPad[lane] = w;
    wPad[lane + 64] = 0.0f;
  }
  __syncthreads();

  // tap arrays (all 256 threads): index n = (i-j)+63 in [0,126]
  for (int idx = tid; idx < 384; idx += 256) {
    const int c = idx >> 7, n = idx & 127;
    float v;
    if (c == 0)      v = (n >= 63 && n < 127) ? sArr[n - 63] : 0.0f;  // S: s[i-j]
    else if (c == 1) v = (n >= 63 && n < 127) ? gArr[n - 63] : 0.0f;  // G2: g[i-j]
    else             v = (n < 63) ? gArr[n + 1] : 0.0f;               // G1: g[(i-j)+64]
    taps[c][n] = v;
  }
  __syncthreads();

  // ---------------- fragments from taps (registers, one-time) -------------
  bf16x8 sH[2], sL[2], g2H[2], g2L[2], g1H[2], g1L[2], aH[2], aL[2];
  #pragma unroll
  for (int tk = 0; tk < 2; ++tk) {
    const int n0 = 16 * wq + ln16 - (32 * tk + 8 * quad) + 63;
    gen_frag(taps[0], n0, sH[tk], sL[tk]);
    gen_frag(taps[1], n0, g2H[tk], g2L[tk]);
    gen_frag(taps[2], n0, g1H[tk], g1L[tk]);
  }

  // ---------------- A = S·W precompute (MFMA, 4-term hi/lo) ----------------
  {
    f32x4 accA[4];
    #pragma unroll
    for (int nt = 0; nt < 4; ++nt) accA[nt] = (f32x4){0.f, 0.f, 0.f, 0.f};
    #pragma unroll
    for (int nt = 0; nt < 4; ++nt) {
      #pragma unroll
      for (int tk = 0; tk < 2; ++tk) {
        // W as B-operand: B[k][c] = w[(k-c)+63], k = 8*quad+32*tk+j, c = 16*nt+ln16
        float t[8];
        #pragma unroll
        for (int j = 0; j < 8; ++j)
          t[j] = wPad[(8 * quad + 32 * tk + j) - (16 * nt + ln16) + 63];
        const f32x4 a = {t[0], t[1], t[2], t[3]};
        const f32x4 b = {t[4], t[5], t[6], t[7]};
        bf16x8 wh, wl;
        cvt_split8(a, b, wh, wl);
        accA[nt] = MFMA(sH[tk], wh, accA[nt]);
        accA[nt] = MFMA(sH[tk], wl, accA[nt]);
        accA[nt] = MFMA(sL[tk], wh, accA[nt]);
        accA[nt] = MFMA(sL[tk], wl, accA[nt]);   // include LL: A error ~2^-16
      }
    }
    #pragma unroll
    for (int nt = 0; nt < 4; ++nt) {
      #pragma unroll
      for (int r = 0; r < 4; ++r)
        Abuf[16 * wq + 4 * quad + r][16 * nt + ln16] = accA[nt][r];
    }
  }
  __syncthreads();
  #pragma unroll
  for (int tk = 0; tk < 2; ++tk) {
    const int row = 16 * wq + ln16;
    const int k0 = 32 * tk + 8 * quad;
    const f32x4 a = *(const f32x4*)&Abuf[row][k0];
    const f32x4 b = *(const f32x4*)&Abuf[row][k0 + 4];
    cvt_split8(a, b, aH[tk], aL[tk]);
  }

  // ---------------- main chunk loop ----------------------------------------
  bf16x8 pH[2], pL[2];
  {
    bf16x8 z;
    #pragma unroll
    for (int j = 0; j < 8; ++j) z[j] = 0;
    pH[0] = z; pH[1] = z; pL[0] = z; pL[1] = z;
  }

  // u as B-operand: lane loads its own k-range (no wq term); all waves share
  const float* ub = u + ((size_t)ln16 * kH + h) * kL + 8 * quad;
  // y store in C layout: wave's rows = time positions
  float* yp = y + ((size_t)ln16 * kH + h) * kL + 16 * wq + 4 * quad;
  const int ewrow = 16 * wq + 4 * quad;

  f32x4 uv[4];   // [tk*2 + half] prefetch of this chunk's u B-fragment data
  #pragma unroll
  for (int i = 0; i < 4; ++i)
    uv[i] = *(const f32x4*)(ub + 32 * (i >> 1) + 4 * (i & 1));

  int buf = 0;
  for (int m = 0; m < kChunks; ++m) {
    const int t0 = m * 64;
    // u fragments (hi/lo) for this chunk
    bf16x8 uH[2], uL[2];
    cvt_split8(uv[0], uv[1], uH[0], uL[0]);
    cvt_split8(uv[2], uv[3], uH[1], uL[1]);
    // prefetch next chunk (stays in flight across the raw barrier)
    const int tn = (m < kChunks - 1) ? t0 + 64 : t0;
    #pragma unroll
    for (int i = 0; i < 4; ++i)
      uv[i] = *(const f32x4*)(ub + tn + 32 * (i >> 1) + 4 * (i & 1));

    // r = A·p + S·u   (A·p is the recurrent critical path — issue first)
    f32x4 accP = {};
    #pragma unroll
    for (int tk = 0; tk < 2; ++tk) {
      accP = MFMA(aH[tk], pH[tk], accP);
      accP = MFMA(aH[tk], pL[tk], accP);
      accP = MFMA(aL[tk], pH[tk], accP);
    }
    f32x4 accU = {};
    #pragma unroll
    for (int tk = 0; tk < 2; ++tk) {
      accU = MFMA(sH[tk], uH[tk], accU);
      accU = MFMA(sH[tk], uL[tk], accU);
      accU = MFMA(sL[tk], uH[tk], accU);
    }
    // y partial: G1·p (previous chunk's r window)
    f32x4 accY = {};
    #pragma unroll
    for (int tk = 0; tk < 2; ++tk) {
      accY = MFMA(g1H[tk], pH[tk], accY);
      accY = MFMA(g1H[tk], pL[tk], accY);
      accY = MFMA(g1L[tk], pH[tk], accY);
    }
    const f32x4 accR = accP + accU;
    *(f32x4*)&Rbuf[buf][ln16][ewrow] = accR;
    // raw barrier: drain LDS writes only — global loads/stores stay in flight
    asm volatile("s_waitcnt lgkmcnt(0)" ::: "memory");
    __builtin_amdgcn_s_barrier();
    asm volatile("" ::: "memory");

    // r fragments = next chunk's p fragments (read once, used twice)
    #pragma unroll
    for (int tk = 0; tk < 2; ++tk) {
      const int k0 = 8 * quad + 32 * tk;
      const f32x4 ra = *(const f32x4*)&Rbuf[buf][ln16][k0];
      const f32x4 rb = *(const f32x4*)&Rbuf[buf][ln16][k0 + 4];
      cvt_split8(ra, rb, pH[tk], pL[tk]);
    }
    // accY += G2·r
    f32x4 accY2 = accY;
    #pragma unroll
    for (int tk = 0; tk < 2; ++tk) {
      accY2 = MFMA(g2H[tk], pH[tk], accY2);
      accY2 = MFMA(g2H[tk], pL[tk], accY2);
      accY2 = MFMA(g2L[tk], pH[tk], accY2);
    }
    *(f32x4*)(yp + t0) = accY2;
    buf ^= 1;
    // Rbuf double-buffer: chunk m+1 writes buf^1, so a fast wave can never
    // overwrite a buffer a slow wave is still reading (write of `buf` again
    // only happens after the NEXT barrier, which orders it past all reads).
  }
}

}  // namespace

extern "C" void kernel_launch(void* const* d_in, const int* in_sizes, int n_in,
                              void* d_out, int out_size, void* d_ws, size_t ws_size,
                              hipStream_t stream) {
  const float* u  = (const float*)d_in[0];   // (16, 512, 2048) fp32
  const float* kk = (const float*)d_in[1];   // (1, 512, 64)    fp32
  if (n_in >= 2 && in_sizes[0] < in_sizes[1]) {
    const float* t = u; u = kk; kk = t;
  }
  float* y = (float*)d_out;                  // (16, 512, 2048) fp32
  hipLaunchKernelGGL(ssm_mfma_kernel, dim3(kH), dim3(256), 0, stream, u, kk, y);
}

// Round 2
// 145.895 us; speedup vs baseline: 1.0601x; 1.0601x over previous
//
#include <hip/hip_runtime.h>

// StateSpaceDiffusionModel — MFMA formulation, round 4: one wave per head.
//
// Scalar collapse (HW-verified):
//   r_t = u_t + sum_{j=0}^{63} w_j r_{t-1-j},   y_t = sum_{j=0}^{63} g_j r_{t-j}
// Chunked by 64:  r = A·p + S·u  (A = S·W dense, precomputed by MFMA),
//                 y = G1·p + G2·r
// NEW this round: ONE 64-lane wave owns the whole head (4 M-tiles per product,
// same total MFMA count as the old 4-wave version). Consequences:
//   - zero barriers (64-thread block = 1 wave); the r->p redistribution is an
//     intra-wave LDS round-trip (4 ds_write_b128 + lgkmcnt(0) + 4 ds_read_b128)
//     with the G1·p MFMA phase overlapping the write->read window;
//   - u prefetch depth 2 (named uvA/uvB, loop unrolled x2 — rule #20) covers
//     ~900cy HBM latency;
//   - A,S operator fragments live in registers (128 VGPR — occupancy is
//     irrelevant: parallelism is head-limited at 2 waves/CU);
//   - G1,G2 fragments precomputed per-lane into LDS tables (32 KiB), read as
//     conflict-free lane*16B ds_read_b128.
// Math path identical to round 3 (same A collapse, 3-term hi/lo) -> same error.
//
// mfma_f32_16x16x32_bf16 layouts (m89/m120):
//   A[m][k]: m=lane&15, k=(lane>>4)*8+j (+32*tk)
//   B[k][n]: k=(lane>>4)*8+j (+32*tk), n=lane&15
//   C[m][n]: n=lane&15, m=(lane>>4)*4+reg

namespace {

constexpr int kH = 512;
constexpr int kL = 2048;
constexpr int kChunks = 32;
constexpr int kStride = 68;   // LDS row stride (floats): 68 = 4*17

typedef __attribute__((ext_vector_type(8))) short bf16x8;
typedef __attribute__((ext_vector_type(4))) float f32x4;

#define MFMA(A, B, C) __builtin_amdgcn_mfma_f32_16x16x32_bf16((A), (B), (C), 0, 0, 0)

__device__ inline unsigned int cvt_pk_bf16(float lo, float hi) {
  unsigned int r;
  asm("v_cvt_pk_bf16_f32 %0, %1, %2" : "=v"(r) : "v"(lo), "v"(hi));
  return r;
}

union B8U4 { bf16x8 v; unsigned int u[4]; };

// split 8 fp32 (two f32x4) into hi/lo bf16 fragments via packed RNE cvt
__device__ inline void cvt_split8(const f32x4 a, const f32x4 b, bf16x8& fh, bf16x8& fl) {
  B8U4 H, L;
  float x[8];
  #pragma unroll
  for (int j = 0; j < 4; ++j) { x[j] = a[j]; x[4 + j] = b[j]; }
  #pragma unroll
  for (int d = 0; d < 4; ++d) {
    const float x0 = x[2 * d], x1 = x[2 * d + 1];
    const unsigned int hp = cvt_pk_bf16(x0, x1);
    const float h0 = __uint_as_float(hp << 16);
    const float h1 = __uint_as_float(hp & 0xFFFF0000u);
    H.u[d] = hp;
    L.u[d] = cvt_pk_bf16(x0 - h0, x1 - h1);
  }
  fh = H.v; fl = L.v;
}

// Toeplitz A-operand fragment from a 128-tap array: value = tp[n0 - j]
__device__ inline void gen_frag(const float* tp, int n0, bf16x8& fh, bf16x8& fl) {
  float t[8];
  #pragma unroll
  for (int j = 0; j < 8; ++j) {
    const int n = n0 - j;
    t[j] = (n >= 0 && n < 127) ? tp[n] : 0.0f;
  }
  const f32x4 a = {t[0], t[1], t[2], t[3]};
  const f32x4 b = {t[4], t[5], t[6], t[7]};
  cvt_split8(a, b, fh, fl);
}

__global__ __launch_bounds__(64, 1)
void ssm_mfma_kernel(const float* __restrict__ u,
                     const float* __restrict__ kin,
                     float* __restrict__ y) {
  const int h    = blockIdx.x;
  const int lane = threadIdx.x;
  const int ln16 = lane & 15;    // batch col (B/C) / row m (A)
  const int quad = lane >> 4;

  __shared__ float taps[3][128];       // 0=S, 1=G2, 2=G1
  __shared__ float wPad[128];
  __shared__ float Abuf[64][kStride];  // A = S·W (dense, fp32)
  __shared__ float Rbuf[16][kStride];  // [batch][time-in-chunk]
  __shared__ bf16x8 g2T[4][2][2][64];  // [mt][tk][H/L][lane] fragment tables
  __shared__ bf16x8 g1T[4][2][2][64];

  // ---------------- prologue: single wave, shuffle scans -------------------
  const float kv = kin[h * 64 + lane];
  const float kc = fminf(fmaxf(kv, 0.0625f), 1.0f);
  float ks = kc;
  #pragma unroll
  for (int off = 32; off >= 1; off >>= 1) ks += __shfl_xor(ks, off);
  const float kn = kc / ks;
  const float cc = 1.0f / (1.0f + kn);
  // exclusive prefix product of cc across lanes
  float pp = cc;
  #pragma unroll
  for (int off = 1; off < 64; off <<= 1) {
    const float t = __shfl_up(pp, off);
    if (lane >= off) pp *= t;
  }
  float Pe = __shfl_up(pp, 1);
  if (lane == 0) Pe = 1.0f;
  const float w = (lane < 63) ? (kn * cc * Pe) : Pe;
  const float g = kv * Pe;
  // impulse response s_0..s_63: serial shuffle recurrence (wave-local)
  float s = (lane == 0) ? 1.0f : 0.0f;
  for (int rr = 0; rr < 63; ++rr) {
    const float sv = __shfl(s, rr);
    const float cf = __shfl(w, lane - 1 - rr);
    if (lane > rr) s = fmaf(cf, sv, s);
  }
  // tap arrays: index n = (i-j)+63 in [0,126]
  taps[0][lane] = 0.0f;                    // S zeros (idx 63 overwritten below)
  taps[1][lane] = 0.0f;                    // G2 zeros
  const float gn = __shfl(g, lane + 1);
  taps[2][lane] = (lane < 63) ? gn : 0.0f; // G1: g[(i-j)+64]
  taps[2][64 + lane] = 0.0f;
  taps[0][63 + lane] = s;                  // S: s[i-j]
  taps[1][63 + lane] = g;                  // G2: g[i-j]
  wPad[lane] = w;
  wPad[64 + lane] = 0.0f;
  __syncthreads();

  // ---------------- S fragments (regs) + G fragment tables (LDS) ----------
  bf16x8 sH[4][2], sL[4][2], aH[4][2], aL[4][2];
  #pragma unroll
  for (int mt = 0; mt < 4; ++mt) {
    #pragma unroll
    for (int tk = 0; tk < 2; ++tk) {
      const int n0 = 16 * mt + ln16 - (32 * tk + 8 * quad) + 63;
      gen_frag(taps[0], n0, sH[mt][tk], sL[mt][tk]);
      bf16x8 fh, fl;
      gen_frag(taps[1], n0, fh, fl);
      g2T[mt][tk][0][lane] = fh;
      g2T[mt][tk][1][lane] = fl;
      gen_frag(taps[2], n0, fh, fl);
      g1T[mt][tk][0][lane] = fh;
      g1T[mt][tk][1][lane] = fl;
    }
  }

  // ---------------- A = S·W precompute (MFMA, 4-term hi/lo) ----------------
  {
    bf16x8 wh[4][2], wl[4][2];
    #pragma unroll
    for (int nt = 0; nt < 4; ++nt) {
      #pragma unroll
      for (int tk = 0; tk < 2; ++tk) {
        // W as B-operand: B[k][c] = w[(k-c)+63], k = 8*quad+32*tk+j, c = 16*nt+ln16
        float t[8];
        #pragma unroll
        for (int j = 0; j < 8; ++j)
          t[j] = wPad[(8 * quad + 32 * tk + j) - (16 * nt + ln16) + 63];
        const f32x4 a = {t[0], t[1], t[2], t[3]};
        const f32x4 b = {t[4], t[5], t[6], t[7]};
        cvt_split8(a, b, wh[nt][tk], wl[nt][tk]);
      }
    }
    #pragma unroll
    for (int mt = 0; mt < 4; ++mt) {
      f32x4 accA[4];
      #pragma unroll
      for (int nt = 0; nt < 4; ++nt) accA[nt] = (f32x4){0.f, 0.f, 0.f, 0.f};
      #pragma unroll
      for (int nt = 0; nt < 4; ++nt) {
        #pragma unroll
        for (int tk = 0; tk < 2; ++tk) {
          accA[nt] = MFMA(sH[mt][tk], wh[nt][tk], accA[nt]);
          accA[nt] = MFMA(sH[mt][tk], wl[nt][tk], accA[nt]);
          accA[nt] = MFMA(sL[mt][tk], wh[nt][tk], accA[nt]);
          accA[nt] = MFMA(sL[mt][tk], wl[nt][tk], accA[nt]);  // LL: A err ~2^-16
        }
      }
      #pragma unroll
      for (int nt = 0; nt < 4; ++nt) {
        #pragma unroll
        for (int r = 0; r < 4; ++r)
          Abuf[16 * mt + 4 * quad + r][16 * nt + ln16] = accA[nt][r];
      }
    }
  }
  __syncthreads();
  #pragma unroll
  for (int mt = 0; mt < 4; ++mt) {
    #pragma unroll
    for (int tk = 0; tk < 2; ++tk) {
      const int row = 16 * mt + ln16;
      const int k0 = 32 * tk + 8 * quad;
      const f32x4 a = *(const f32x4*)&Abuf[row][k0];
      const f32x4 b = *(const f32x4*)&Abuf[row][k0 + 4];
      cvt_split8(a, b, aH[mt][tk], aL[mt][tk]);
    }
  }

  // ---------------- main chunk loop (barrier-free) --------------------------
  bf16x8 pH[2], pL[2];
  {
    bf16x8 z;
    #pragma unroll
    for (int j = 0; j < 8; ++j) z[j] = 0;
    pH[0] = z; pH[1] = z; pL[0] = z; pL[1] = z;
  }

  // u as B-operand: lane loads its own k-range (batch=ln16, times 8*quad+...)
  const float* ub = u + ((size_t)ln16 * kH + h) * kL + 8 * quad;
  // y store in C layout: rows = time positions 16*mt + 4*quad + reg
  float* yp = y + ((size_t)ln16 * kH + h) * kL + 4 * quad;

  auto chunk = [&](f32x4 (&uvC)[4], int t0, int tpre) {
    // u fragments (hi/lo) for this chunk; then issue prefetch 2 chunks ahead
    bf16x8 uH[2], uL[2];
    cvt_split8(uvC[0], uvC[1], uH[0], uL[0]);
    cvt_split8(uvC[2], uvC[3], uH[1], uL[1]);
    #pragma unroll
    for (int i = 0; i < 4; ++i)
      uvC[i] = *(const f32x4*)(ub + tpre + 32 * (i >> 1) + 4 * (i & 1));

    // r = A·p + S·u   (8 independent 6-deep MFMA chains, issue-bound)
    f32x4 accR[4], accY[4];
    #pragma unroll
    for (int mt = 0; mt < 4; ++mt) {
      accR[mt] = (f32x4){0.f, 0.f, 0.f, 0.f};
      accY[mt] = (f32x4){0.f, 0.f, 0.f, 0.f};
    }
    #pragma unroll
    for (int mt = 0; mt < 4; ++mt) {
      #pragma unroll
      for (int tk = 0; tk < 2; ++tk) {
        accR[mt] = MFMA(aH[mt][tk], pH[tk], accR[mt]);
        accR[mt] = MFMA(aH[mt][tk], pL[tk], accR[mt]);
        accR[mt] = MFMA(aL[mt][tk], pH[tk], accR[mt]);
      }
      #pragma unroll
      for (int tk = 0; tk < 2; ++tk) {
        accR[mt] = MFMA(sH[mt][tk], uH[tk], accR[mt]);
        accR[mt] = MFMA(sH[mt][tk], uL[tk], accR[mt]);
        accR[mt] = MFMA(sL[mt][tk], uH[tk], accR[mt]);
      }
    }
    // write r (C layout transposed to Rbuf[batch][time], contiguous f32x4)
    #pragma unroll
    for (int mt = 0; mt < 4; ++mt)
      *(f32x4*)&Rbuf[ln16][16 * mt + 4 * quad] = accR[mt];

    // y partial: G1·p — overlaps the r write->read LDS latency
    #pragma unroll
    for (int mt = 0; mt < 4; ++mt) {
      #pragma unroll
      for (int tk = 0; tk < 2; ++tk) {
        const bf16x8 gh = g1T[mt][tk][0][lane];
        const bf16x8 gl = g1T[mt][tk][1][lane];
        accY[mt] = MFMA(gh, pH[tk], accY[mt]);
        accY[mt] = MFMA(gh, pL[tk], accY[mt]);
        accY[mt] = MFMA(gl, pH[tk], accY[mt]);
      }
    }

    // intra-wave LDS round-trip: drain writes, then read r in B layout
    asm volatile("s_waitcnt lgkmcnt(0)" ::: "memory");
    __builtin_amdgcn_sched_barrier(0);
    #pragma unroll
    for (int tk = 0; tk < 2; ++tk) {
      const int k0 = 8 * quad + 32 * tk;
      const f32x4 ra = *(const f32x4*)&Rbuf[ln16][k0];
      const f32x4 rb = *(const f32x4*)&Rbuf[ln16][k0 + 4];
      cvt_split8(ra, rb, pH[tk], pL[tk]);   // r fragments = next chunk's p
    }

    // accY += G2·r ; store y
    #pragma unroll
    for (int mt = 0; mt < 4; ++mt) {
      #pragma unroll
      for (int tk = 0; tk < 2; ++tk) {
        const bf16x8 gh = g2T[mt][tk][0][lane];
        const bf16x8 gl = g2T[mt][tk][1][lane];
        accY[mt] = MFMA(gh, pH[tk], accY[mt]);
        accY[mt] = MFMA(gh, pL[tk], accY[mt]);
        accY[mt] = MFMA(gl, pH[tk], accY[mt]);
      }
      *(f32x4*)(yp + t0 + 16 * mt) = accY[mt];
    }
  };

  // u prefetch depth 2: named buffers, loop unrolled x2 (rule #20: no runtime
  // indexing of register arrays)
  f32x4 uvA[4], uvB[4];
  #pragma unroll
  for (int i = 0; i < 4; ++i) {
    uvA[i] = *(const f32x4*)(ub + 32 * (i >> 1) + 4 * (i & 1));
    uvB[i] = *(const f32x4*)(ub + 64 + 32 * (i >> 1) + 4 * (i & 1));
  }
  for (int m = 0; m < kChunks; m += 2) {
    const int t0 = m * 64;
    chunk(uvA, t0,      (t0 + 128 < kL) ? (t0 + 128) : 0);
    chunk(uvB, t0 + 64, (t0 + 192 < kL) ? (t0 + 192) : 0);
  }
}

}  // namespace

extern "C" void kernel_launch(void* const* d_in, const int* in_sizes, int n_in,
                              void* d_out, int out_size, void* d_ws, size_t ws_size,
                              hipStream_t stream) {
  const float* u  = (const float*)d_in[0];   // (16, 512, 2048) fp32
  const float* kk = (const float*)d_in[1];   // (1, 512, 64)    fp32
  if (n_in >= 2 && in_sizes[0] < in_sizes[1]) {
    const float* t = u; u = kk; kk = t;
  }
  float* y = (float*)d_out;                  // (16, 512, 2048) fp32
  hipLaunchKernelGGL(ssm_mfma_kernel, dim3(kH), dim3(64), 0, stream, u, kk, y);
}